// Round 12
// baseline (672.196 us; speedup 1.0000x reference)
//
#include <hip/hip_runtime.h>
#include <hip/hip_bf16.h>

typedef __attribute__((ext_vector_type(8))) short short8;
typedef __attribute__((ext_vector_type(4))) float f32x4;

#define AS1 __attribute__((address_space(1)))
#define AS3 __attribute__((address_space(3)))

static __device__ __forceinline__ short f2bf(float f) {
    __hip_bfloat16 h = __float2bfloat16(f);
    union { __hip_bfloat16 h; short s; } u;
    u.h = h;
    return u.s;
}

// ---------------- prepack kernels ----------------

__global__ __launch_bounds__(256) void prepack_w_kernel(const int* __restrict__ wq,
                                                        const float* __restrict__ scales,
                                                        short* __restrict__ Wb,
                                                        long total8) {
    long i = (long)blockIdx.x * 256 + threadIdx.x;
    if (i >= total8) return;
    const int4* p = (const int4*)wq + i * 2;
    int4 q0 = p[0], q1 = p[1];
    float s = scales[(i * 8) >> 5];
    short8 v;
    v[0] = f2bf((float)(q0.x - 128) * s);
    v[1] = f2bf((float)(q0.y - 128) * s);
    v[2] = f2bf((float)(q0.z - 128) * s);
    v[3] = f2bf((float)(q0.w - 128) * s);
    v[4] = f2bf((float)(q1.x - 128) * s);
    v[5] = f2bf((float)(q1.y - 128) * s);
    v[6] = f2bf((float)(q1.z - 128) * s);
    v[7] = f2bf((float)(q1.w - 128) * s);
    ((short8*)Wb)[i] = v;
}

__global__ __launch_bounds__(256) void prepack_x_kernel(const float* __restrict__ x,
                                                        short* __restrict__ Xb,
                                                        long total8) {
    long i = (long)blockIdx.x * 256 + threadIdx.x;
    if (i >= total8) return;
    const float4* p = (const float4*)x + i * 2;
    float4 f0 = p[0], f1 = p[1];
    short8 v;
    v[0] = f2bf(f0.x); v[1] = f2bf(f0.y); v[2] = f2bf(f0.z); v[3] = f2bf(f0.w);
    v[4] = f2bf(f1.x); v[5] = f2bf(f1.y); v[6] = f2bf(f1.z); v[7] = f2bf(f1.w);
    ((short8*)Xb)[i] = v;
}

// ------------- 256x256 GEMM: 8-phase, A 3-buffer / B 2-buffer, VMC(8) -------------
// 512 thr = 8 waves (2M x 4N), per-wave C = 128x64, BK=64, mfma 16x16x32.
// LDS 160 KB exactly: As[3 slots][2 halves][128x64 bf16] = 96 KB,
//                     Bs[2 par  ][2 halves][128x64 bf16] = 64 KB.
// Granule(16B) XOR swizzle (slot g of row r holds global granule g^(r&7)) -- the
// R5/R10 0-conflict mapping, unchanged.
// Per tile t (4 phases, R5 skeleton): ph_q reads A band q (QUAD) + B all (ph0);
// stages: A(t+2)h0@ph0, A(t+2)h1@ph1 -> slot[(t+2)%3];
//         B(t+2)h0@ph2, B(t+2)h1@ph3 -> par[t&1].
// WAR: A slot (t+2)%3 == (t-1)%3, its reads end at t-1 ph3 (lgkm0 < trailing BAR);
//      B par[t] reads complete at ph0 (lgkm0 < ph0 trailing BAR) -> ph2/3 safe.
// Ledger: at each tile start, in-flight = A(t+1)4 + B(t+1)4 = 8 (issued LAST tile,
// >=4 phases old). During tile: +8 (A(t+2),B(t+2)) -> 16; VMC(8) at ph3 forces
// exactly A(t+1)+B(t+1) (old, cheap) and keeps the 8 fresh ones in flight.
__global__ __launch_bounds__(512, 2)
void gemm256_kernel(const float* __restrict__ bias,
                    const short* __restrict__ Xb, const short* __restrict__ Wb,
                    float* __restrict__ out, int M, int N, int K) {
    __shared__ alignas(16) short As[3 * 16384];
    __shared__ alignas(16) short Bs[2 * 16384];

    const int nM = M >> 8, nN = N >> 8;
    int bid = blockIdx.x;
    {
        int nwg = nM * nN;
        if ((nwg & 7) == 0) bid = (bid & 7) * (nwg >> 3) + (bid >> 3);  // XCD swizzle
    }
    int pm, pn;
    {
        const int G = 8;
        if ((nN % G) == 0) {
            int per = nM * G;
            int grp = bid / per, in = bid % per;
            pn = grp * G + (in % G);
            pm = in / G;
        } else { pn = bid % nN; pm = bid / nN; }
    }

    const int tid  = threadIdx.x;
    const int lane = tid & 63;
    const int wid  = tid >> 6;
    const int wm   = wid >> 2;     // 0..1
    const int wn   = wid & 3;      // 0..3
    const int q4   = lane >> 4;
    const int l15  = lane & 15;
    const int lx   = lane & 7;

    const long bm = (long)pm << 8, bn = (long)pn << 8;
    const long Kl = K;
    const int  NT = K >> 6;

    // read bases (shorts); slot/par offsets added as literals per TILE
    const int rAb = wm * 8192 + l15 * 64;                          // + slot*16384
    const int rBb = (wn >> 1) * 8192 + ((wn & 1) * 64 + l15) * 64; // + par*16384
    const int sgk0 = ((0 + q4) ^ lx) * 8;   // kk=0 granule (swizzled)
    const int sgk1 = ((4 + q4) ^ lx) * 8;   // kk=1

    // staging geometry (identical to R5/R10)
    const int chnk    = wid * 1024;
    const int srowrel = wid * 16 + (lane >> 3);
    const int scol    = ((lane & 7) ^ (lane >> 3)) * 8;

    const short* aS00 = Xb + (bm + 0   + srowrel + 0) * Kl + scol;
    const short* aS01 = Xb + (bm + 0   + srowrel + 8) * Kl + scol;
    const short* aS10 = Xb + (bm + 128 + srowrel + 0) * Kl + scol;
    const short* aS11 = Xb + (bm + 128 + srowrel + 8) * Kl + scol;
    const short* bS00 = Wb + (bn + 0   + srowrel + 0) * Kl + scol;
    const short* bS01 = Wb + (bn + 0   + srowrel + 8) * Kl + scol;
    const short* bS10 = Wb + (bn + 128 + srowrel + 0) * Kl + scol;
    const short* bS11 = Wb + (bn + 128 + srowrel + 8) * Kl + scol;

#define STGA(H, SLOT, OFF) {                                                          \
    __builtin_amdgcn_global_load_lds((const AS1 void*)(aS##H##0 + (OFF)),             \
        (AS3 void*)&As[(SLOT) * 16384 + (H) * 8192 + chnk], 16, 0, 0);                \
    __builtin_amdgcn_global_load_lds((const AS1 void*)(aS##H##1 + (OFF)),             \
        (AS3 void*)&As[(SLOT) * 16384 + (H) * 8192 + chnk + 512], 16, 0, 0); }
#define STGB(H, PAR, OFF) {                                                           \
    __builtin_amdgcn_global_load_lds((const AS1 void*)(bS##H##0 + (OFF)),             \
        (AS3 void*)&Bs[(PAR) * 16384 + (H) * 8192 + chnk], 16, 0, 0);                 \
    __builtin_amdgcn_global_load_lds((const AS1 void*)(bS##H##1 + (OFF)),             \
        (AS3 void*)&Bs[(PAR) * 16384 + (H) * 8192 + chnk + 512], 16, 0, 0); }

// A band reads for phase Q: m-frags 2Q, 2Q+1, both kk (4 x b128)
#define QUAD(Q, SLOT) {                                                               \
    ak[0][0] = *(const short8*)&As[(SLOT) * 16384 + rAb + (2*(Q)) * 1024 + sgk0];     \
    ak[0][1] = *(const short8*)&As[(SLOT) * 16384 + rAb + (2*(Q)) * 1024 + sgk1];     \
    ak[1][0] = *(const short8*)&As[(SLOT) * 16384 + rAb + (2*(Q)+1) * 1024 + sgk0];   \
    ak[1][1] = *(const short8*)&As[(SLOT) * 16384 + rAb + (2*(Q)+1) * 1024 + sgk1]; }

// all 8 B frags (4 n x 2 kk)
#define LDB8(PAR) { _Pragma("unroll") for (int n = 0; n < 4; ++n) {                   \
    bfr[n][0] = *(const short8*)&Bs[(PAR) * 16384 + rBb + n * 1024 + sgk0];           \
    bfr[n][1] = *(const short8*)&Bs[(PAR) * 16384 + rBb + n * 1024 + sgk1]; } }

#define MFMA16(Q) { __builtin_amdgcn_s_setprio(1);                                    \
    _Pragma("unroll") for (int mi = 0; mi < 2; ++mi) {                                \
        _Pragma("unroll") for (int n = 0; n < 4; ++n)                                 \
            acc[2*(Q)+mi][n] = __builtin_amdgcn_mfma_f32_16x16x32_bf16(               \
                ak[mi][0], bfr[n][0], acc[2*(Q)+mi][n], 0, 0, 0);                     \
        _Pragma("unroll") for (int n = 0; n < 4; ++n)                                 \
            acc[2*(Q)+mi][n] = __builtin_amdgcn_mfma_f32_16x16x32_bf16(               \
                ak[mi][1], bfr[n][1], acc[2*(Q)+mi][n], 0, 0, 0); }                   \
    __builtin_amdgcn_s_setprio(0); }

#define BAR  __builtin_amdgcn_s_barrier()
#define WLGN(n) { asm volatile("s_waitcnt lgkmcnt(" #n ")" ::: "memory");             \
                  __builtin_amdgcn_sched_barrier(0); }
#define VMC(n)  asm volatile("s_waitcnt vmcnt(" #n ")" ::: "memory")

// One K-tile (R5 phase skeleton). RSLOT: A read slot (0/1/2); RPAR: B read parity;
// S2: A stage slot for t+2; P2: B stage parity for t+2; OFF2: k-offset of t+2.
#define TILE(RSLOT, RPAR, S2, P2, OFF2, DO_S, LAST, DRAIN0) {                         \
    /* ph0 */                                                                         \
    QUAD(0, RSLOT); LDB8(RPAR);                                                       \
    if (DO_S) STGA(0, S2, OFF2);                                                      \
    WLGN(8); BAR; WLGN(0); MFMA16(0); BAR;                                            \
    /* ph1 */                                                                         \
    QUAD(1, RSLOT);                                                                   \
    if (DO_S) STGA(1, S2, OFF2);                                                      \
    BAR; WLGN(0); MFMA16(1); BAR;                                                     \
    /* ph2 */                                                                         \
    QUAD(2, RSLOT);                                                                   \
    if (DO_S) STGB(0, P2, OFF2);                                                      \
    BAR; WLGN(0); MFMA16(2); BAR;                                                     \
    /* ph3 */                                                                         \
    QUAD(3, RSLOT);                                                                   \
    if (DO_S) STGB(1, P2, OFF2);                                                      \
    BAR; WLGN(0); MFMA16(3);                                                          \
    if (!(LAST)) {                                                                    \
        if (DRAIN0) { VMC(0); } else { VMC(8); }                                      \
        BAR;                                                                          \
    } }

    f32x4 acc[8][4];
#pragma unroll
    for (int m = 0; m < 8; ++m)
#pragma unroll
        for (int n = 0; n < 4; ++n) acc[m][n] = (f32x4){0.f, 0.f, 0.f, 0.f};

    short8 ak[2][2], bfr[4][2];

    // ---- prologue: A(0)->slot0,B(0)->par0 first; A(1)->slot1,B(1)->par1 after ----
    STGB(0, 0, 0); STGB(1, 0, 0);
    STGA(0, 0, 0); STGA(1, 0, 0);
    STGA(0, 1, 64); STGA(1, 1, 64);
    STGB(0, 1, 64); STGB(1, 1, 64);
    VMC(8);                       // tile 0 resident; A(1),B(1) in flight (=8)
    BAR;

    // ---- main loop: 6 tiles/iter (LCM of 3-slot x 2-parity), all literals ----
    // tile u: A slot u%3, B par u%2; stages (u+2): A slot (u+2)%3, B par u%2.
    for (int t = 0; t + 9 < NT; t += 6) {
        const long f2 = ((long)t + 2) << 6;
        TILE(0, 0, 2, 0, f2,       true, false, false);
        TILE(1, 1, 0, 1, f2 + 64,  true, false, false);
        TILE(2, 0, 1, 0, f2 + 128, true, false, false);
        TILE(0, 1, 2, 1, f2 + 192, true, false, false);
        TILE(1, 0, 0, 0, f2 + 256, true, false, false);
        TILE(2, 1, 1, 1, f2 + 320, true, false, false);
    }

    // ---- tail: tiles NT-4..NT-1 (requires (NT-4)%6==0 -> slots 0,1,2,0) ----
    {
        const long f2 = ((long)NT - 2) << 6;
        TILE(0, 0, 2, 0, f2,      true,  false, false);   // NT-4 stages NT-2
        TILE(1, 1, 0, 1, f2 + 64, true,  false, false);   // NT-3 stages NT-1
        TILE(2, 0, 0, 0, 0,       false, false, true);    // NT-2: drain VMC(0)
        TILE(0, 1, 0, 0, 0,       false, true,  false);   // NT-1: last
    }

    // ---- epilogue: C/D layout col = lane&15, row = (lane>>4)*4 + reg ----
#pragma unroll
    for (int n = 0; n < 4; ++n) {
        long col = bn + wn * 64 + n * 16 + l15;
        float bv = bias[col];
#pragma unroll
        for (int m = 0; m < 8; ++m) {
            long row = bm + wm * 128 + m * 16 + q4 * 4;
#pragma unroll
            for (int r = 0; r < 4; ++r)
                out[(row + r) * (long)N + col] = acc[m][n][r] + bv;
        }
    }
#undef STGA
#undef STGB
#undef QUAD
#undef LDB8
#undef MFMA16
#undef BAR
#undef WLGN
#undef VMC
#undef TILE
}

// ---------------- fallback 128x128 GEMM (handles fused / odd shapes) ----------------

template <bool PRE_A, bool PRE_B>
__global__ __launch_bounds__(256, 2)
void gemm_kernel(const float* __restrict__ x, const int* __restrict__ wq,
                 const float* __restrict__ scales, const float* __restrict__ bias,
                 const short* __restrict__ Xb, const short* __restrict__ Wb,
                 float* __restrict__ out, int M, int N, int K) {
    constexpr int BM = 128, BN = 128, BK = 64;
    __shared__ alignas(16) short As[BM * BK];
    __shared__ alignas(16) short Bs[BN * BK];

    const int nM = M / BM, nN = N / BN;
    int bid = blockIdx.x;
    int pm, pn;
    const int G = 8;
    if ((nN % G) == 0) {
        int per = nM * G;
        int grp = bid / per;
        int in  = bid % per;
        pn = grp * G + (in % G);
        pm = in / G;
    } else {
        pn = bid % nN;
        pm = bid / nN;
    }

    const int tid  = threadIdx.x;
    const int lane = tid & 63;
    const int wv   = tid >> 6;
    const int wm   = (wv >> 1) * 64;
    const int wn   = (wv & 1) * 64;
    const int q    = lane >> 4;
    const int l15  = lane & 15;
    const int sxor = lane & 7;

    const long bm = (long)pm * BM, bn = (long)pn * BN;

    f32x4 acc[4][4];
#pragma unroll
    for (int i = 0; i < 4; ++i)
#pragma unroll
        for (int j = 0; j < 4; ++j) acc[i][j] = (f32x4){0.f, 0.f, 0.f, 0.f};

    const int srow = tid >> 3;
    const int scg  = tid & 7;

    const int sg0   = q ^ sxor;
    const int aOff0 = (wm + l15) * 64 + sg0 * 8;
    const int aOff1 = (wm + l15) * 64 + (sg0 ^ 4) * 8;
    const int bOff0 = (wn + l15) * 64 + sg0 * 8;
    const int bOff1 = (wn + l15) * 64 + (sg0 ^ 4) * 8;

    const int prRow  = lane >> 3;
    const int prGsrc = (lane & 7) ^ (lane >> 3);

    for (int k0 = 0; k0 < K; k0 += BK) {
        if constexpr (PRE_A) {
#pragma unroll
            for (int i = 0; i < 4; ++i) {
                int r = wv * 32 + i * 8 + prRow;
                const short* src = Xb + (bm + r) * (long)K + k0 + prGsrc * 8;
                __builtin_amdgcn_global_load_lds((const AS1 void*)src,
                                                 (AS3 void*)&As[(wv * 32 + i * 8) * 64],
                                                 16, 0, 0);
            }
        } else {
#pragma unroll
            for (int i = 0; i < 4; ++i) {
                int r = i * 32 + srow;
                const float4* p = (const float4*)(x + (bm + r) * (long)K + k0 + scg * 8);
                float4 f0 = p[0], f1 = p[1];
                short8 v;
                v[0] = f2bf(f0.x); v[1] = f2bf(f0.y); v[2] = f2bf(f0.z); v[3] = f2bf(f0.w);
                v[4] = f2bf(f1.x); v[5] = f2bf(f1.y); v[6] = f2bf(f1.z); v[7] = f2bf(f1.w);
                int sg = scg ^ (r & 7);
                *(short8*)&As[r * 64 + sg * 8] = v;
            }
        }
        if constexpr (PRE_B) {
#pragma unroll
            for (int i = 0; i < 4; ++i) {
                int r = wv * 32 + i * 8 + prRow;
                const short* src = Wb + (bn + r) * (long)K + k0 + prGsrc * 8;
                __builtin_amdgcn_global_load_lds((const AS1 void*)src,
                                                 (AS3 void*)&Bs[(wv * 32 + i * 8) * 64],
                                                 16, 0, 0);
            }
        } else {
#pragma unroll
            for (int i = 0; i < 4; ++i) {
                int r = i * 32 + srow;
                const int4* p = (const int4*)(wq + (bn + r) * (long)K + k0 + scg * 8);
                int4 q0 = p[0], q1 = p[1];
                float s = scales[(bn + r) * (long)(K >> 5) + ((k0 + scg * 8) >> 5)];
                short8 v;
                v[0] = f2bf((float)(q0.x - 128) * s);
                v[1] = f2bf((float)(q0.y - 128) * s);
                v[2] = f2bf((float)(q0.z - 128) * s);
                v[3] = f2bf((float)(q0.w - 128) * s);
                v[4] = f2bf((float)(q1.x - 128) * s);
                v[5] = f2bf((float)(q1.y - 128) * s);
                v[6] = f2bf((float)(q1.z - 128) * s);
                v[7] = f2bf((float)(q1.w - 128) * s);
                int sg = scg ^ (r & 7);
                *(short8*)&Bs[r * 64 + sg * 8] = v;
            }
        }
        __syncthreads();

#pragma unroll
        for (int kk = 0; kk < 2; ++kk) {
            short8 a[4], b[4];
            const int aBase = kk ? aOff1 : aOff0;
            const int bBase = kk ? bOff1 : bOff0;
#pragma unroll
            for (int mi = 0; mi < 4; ++mi) a[mi] = *(const short8*)&As[aBase + mi * 16 * 64];
#pragma unroll
            for (int nj = 0; nj < 4; ++nj) b[nj] = *(const short8*)&Bs[bBase + nj * 16 * 64];
#pragma unroll
            for (int mi = 0; mi < 4; ++mi)
#pragma unroll
                for (int nj = 0; nj < 4; ++nj)
                    acc[mi][nj] = __builtin_amdgcn_mfma_f32_16x16x32_bf16(
                        a[mi], b[nj], acc[mi][nj], 0, 0, 0);
        }
        __syncthreads();
    }

#pragma unroll
    for (int nj = 0; nj < 4; ++nj) {
        long col = bn + wn + nj * 16 + l15;
        float bv = bias[col];
#pragma unroll
        for (int mi = 0; mi < 4; ++mi) {
            long row = bm + wm + mi * 16 + q * 4;
#pragma unroll
            for (int r2 = 0; r2 < 4; ++r2)
                out[(row + r2) * (long)N + col] = acc[mi][nj][r2] + bv;
        }
    }
}

// ---------------- launch ----------------

extern "C" void kernel_launch(void* const* d_in, const int* in_sizes, int n_in,
                              void* d_out, int out_size, void* d_ws, size_t ws_size,
                              hipStream_t stream) {
    const float* x      = (const float*)d_in[0];
    const int*   wq     = (const int*)d_in[1];
    const float* scales = (const float*)d_in[2];
    const float* bias   = (const float*)d_in[3];
    float*       out    = (float*)d_out;

    const long N = (long)in_sizes[3];
    const long K = (long)in_sizes[1] / N;
    const long M = (long)in_sizes[0] / K;

    const size_t needW = (size_t)N * K * sizeof(short);
    const size_t needX = (size_t)M * K * sizeof(short);

    short* Wb = (short*)d_ws;
    short* Xb = Wb + (size_t)N * K;

    const bool preB = (d_ws != nullptr) && ws_size >= needW;
    const bool preA = preB && ws_size >= (needW + needX);

    if (preB) {
        long t8 = N * K / 8;
        prepack_w_kernel<<<dim3((unsigned)((t8 + 255) / 256)), dim3(256), 0, stream>>>(
            wq, scales, Wb, t8);
    }
    if (preA) {
        long t8 = M * K / 8;
        prepack_x_kernel<<<dim3((unsigned)((t8 + 255) / 256)), dim3(256), 0, stream>>>(
            x, Xb, t8);
    }

    const long NTl = K / 64;
    const bool big = preA && (M % 256 == 0) && (N % 256 == 0) && (K % 64 == 0) &&
                     (NTl >= 10) && (NTl % 2 == 0) && (((NTl - 4) % 6) == 0);

    if (big) {
        dim3 grid((unsigned)((M / 256) * (N / 256))), block(512);
        gemm256_kernel<<<grid, block, 0, stream>>>(bias, Xb, Wb, out, (int)M, (int)N, (int)K);
    } else {
        dim3 grid((unsigned)((M / 128) * (N / 128))), block(256);
        if (preA)
            gemm_kernel<true, true><<<grid, block, 0, stream>>>(x, wq, scales, bias, Xb, Wb,
                                                                out, (int)M, (int)N, (int)K);
        else if (preB)
            gemm_kernel<false, true><<<grid, block, 0, stream>>>(x, wq, scales, bias, Xb, Wb,
                                                                 out, (int)M, (int)N, (int)K);
        else
            gemm_kernel<false, false><<<grid, block, 0, stream>>>(x, wq, scales, bias, Xb, Wb,
                                                                  out, (int)M, (int)N, (int)K);
    }
}

// Round 13
// 610.523 us; speedup vs baseline: 1.1010x; 1.1010x over previous
//
#include <hip/hip_runtime.h>
#include <hip/hip_bf16.h>

typedef __attribute__((ext_vector_type(8))) short short8;
typedef __attribute__((ext_vector_type(4))) float f32x4;

#define AS1 __attribute__((address_space(1)))
#define AS3 __attribute__((address_space(3)))

static __device__ __forceinline__ short f2bf(float f) {
    __hip_bfloat16 h = __float2bfloat16(f);
    union { __hip_bfloat16 h; short s; } u;
    u.h = h;
    return u.s;
}

// ---------------- prepack kernels ----------------

__global__ __launch_bounds__(256) void prepack_w_kernel(const int* __restrict__ wq,
                                                        const float* __restrict__ scales,
                                                        short* __restrict__ Wb,
                                                        long total8) {
    long i = (long)blockIdx.x * 256 + threadIdx.x;
    if (i >= total8) return;
    const int4* p = (const int4*)wq + i * 2;
    int4 q0 = p[0], q1 = p[1];
    float s = scales[(i * 8) >> 5];
    short8 v;
    v[0] = f2bf((float)(q0.x - 128) * s);
    v[1] = f2bf((float)(q0.y - 128) * s);
    v[2] = f2bf((float)(q0.z - 128) * s);
    v[3] = f2bf((float)(q0.w - 128) * s);
    v[4] = f2bf((float)(q1.x - 128) * s);
    v[5] = f2bf((float)(q1.y - 128) * s);
    v[6] = f2bf((float)(q1.z - 128) * s);
    v[7] = f2bf((float)(q1.w - 128) * s);
    ((short8*)Wb)[i] = v;
}

__global__ __launch_bounds__(256) void prepack_x_kernel(const float* __restrict__ x,
                                                        short* __restrict__ Xb,
                                                        long total8) {
    long i = (long)blockIdx.x * 256 + threadIdx.x;
    if (i >= total8) return;
    const float4* p = (const float4*)x + i * 2;
    float4 f0 = p[0], f1 = p[1];
    short8 v;
    v[0] = f2bf(f0.x); v[1] = f2bf(f0.y); v[2] = f2bf(f0.z); v[3] = f2bf(f0.w);
    v[4] = f2bf(f1.x); v[5] = f2bf(f1.y); v[6] = f2bf(f1.z); v[7] = f2bf(f1.w);
    ((short8*)Xb)[i] = v;
}

// -------- 256x256 GEMM: anti-phase wave groups, 2 barriers / K-tile --------
// 512 thr = 8 waves (2M x 4N), per-wave C = 128x64 (8 m x 4 n frags), BK=64.
// LDS: A/B each [par*2+half][128x64 bf16], granule(16B) XOR swizzle (0-conflict,
// measured R5/R10).
// ANTI-PHASE: waves 0-3 compute k-step s0 then s1; waves 4-7 compute s1 then s0.
// With round-robin wave->SIMD mapping each SIMD holds one wave of each group, so
// one wave's second A-read burst drains under the other's MFMA cluster.
// Tile t (parity p), per wave:
//   LDB8(p) [8]; RDA8(p, s_first) [8]; STGA(t+1 -> p^1) [4];
//   WLGN(8)  -- own B-reads complete
//   BAR #1   -- ALL waves' B(p)-reads complete  => B(t+2)->p overwrite safe
//   STGB(t+2 -> p) [4]
//   WLGN(0); MFMA32(s_first);
//   RDA8(p, s_second); WLGN(0); MFMA32(s_second);
//   VMC(4); BAR #2 (boundary)
// Ledger: entering tile t in-flight = [B(t+1):4]; +A(t+1)+B(t+2) -> 12;
// VMC(4) forces B(t+1)+A(t+1) (needed next tile), keeps B(t+2) in flight.
// A(t+1)->p^1 overwrite guard: tile t-1's reads of p^1 all complete before
// boundary BAR of t-1 (each wave's WLGN(0) precedes it). Removed R10's two
// mid-tile barriers (they guarded nothing; audit above).
__global__ __launch_bounds__(512, 2)
void gemm256_kernel(const float* __restrict__ bias,
                    const short* __restrict__ Xb, const short* __restrict__ Wb,
                    float* __restrict__ out, int M, int N, int K) {
    __shared__ alignas(16) short As[4 * 8192];
    __shared__ alignas(16) short Bs[4 * 8192];

    const int nM = M >> 8, nN = N >> 8;
    int bid = blockIdx.x;
    {
        int nwg = nM * nN;
        if ((nwg & 7) == 0) bid = (bid & 7) * (nwg >> 3) + (bid >> 3);  // XCD swizzle
    }
    int pm, pn;
    {
        const int G = 8;
        if ((nN % G) == 0) {
            int per = nM * G;
            int grp = bid / per, in = bid % per;
            pn = grp * G + (in % G);
            pm = in / G;
        } else { pn = bid % nN; pm = bid / nN; }
    }

    const int tid  = threadIdx.x;
    const int lane = tid & 63;
    const int wid  = tid >> 6;
    const int wm   = wid >> 2;     // 0..1
    const int wn   = wid & 3;      // 0..3
    const int q4   = lane >> 4;
    const int l15  = lane & 15;
    const int lx   = lane & 7;
    const bool gA  = (wid >> 2) == 0;   // wave group: 0-3 s0-first, 4-7 s1-first

    const long bm = (long)pm << 8, bn = (long)pn << 8;
    const long Kl = K;
    const int  NT = K >> 6;

    // per-parity read bases (shorts); R5/R10's conflict-free pattern
    const int rA0 = wm * 8192 + l15 * 64;
    const int rA1 = (2 + wm) * 8192 + l15 * 64;
    const int rB0 = (wn >> 1) * 8192 + ((wn & 1) * 64 + l15) * 64;
    const int rB1 = rB0 + 2 * 8192;
    const int sg0 = (q4 ^ lx) * 8;        // k-step 0 granule (swizzled)
    const int sg1 = ((4 + q4) ^ lx) * 8;  // k-step 1

    // staging geometry (identical to R5/R10)
    const int chnk    = wid * 1024;
    const int srowrel = wid * 16 + (lane >> 3);
    const int scol    = ((lane & 7) ^ (lane >> 3)) * 8;

    const short* aS00 = Xb + (bm + 0   + srowrel + 0) * Kl + scol;
    const short* aS01 = Xb + (bm + 0   + srowrel + 8) * Kl + scol;
    const short* aS10 = Xb + (bm + 128 + srowrel + 0) * Kl + scol;
    const short* aS11 = Xb + (bm + 128 + srowrel + 8) * Kl + scol;
    const short* bS00 = Wb + (bn + 0   + srowrel + 0) * Kl + scol;
    const short* bS01 = Wb + (bn + 0   + srowrel + 8) * Kl + scol;
    const short* bS10 = Wb + (bn + 128 + srowrel + 0) * Kl + scol;
    const short* bS11 = Wb + (bn + 128 + srowrel + 8) * Kl + scol;

#define STGA(H, PARL, OFF) {                                                          \
    __builtin_amdgcn_global_load_lds((const AS1 void*)(aS##H##0 + (OFF)),             \
        (AS3 void*)&As[((PARL) * 2 + (H)) * 8192 + chnk], 16, 0, 0);                  \
    __builtin_amdgcn_global_load_lds((const AS1 void*)(aS##H##1 + (OFF)),             \
        (AS3 void*)&As[((PARL) * 2 + (H)) * 8192 + chnk + 512], 16, 0, 0); }
#define STGB(H, PARL, OFF) {                                                          \
    __builtin_amdgcn_global_load_lds((const AS1 void*)(bS##H##0 + (OFF)),             \
        (AS3 void*)&Bs[((PARL) * 2 + (H)) * 8192 + chnk], 16, 0, 0);                  \
    __builtin_amdgcn_global_load_lds((const AS1 void*)(bS##H##1 + (OFF)),             \
        (AS3 void*)&Bs[((PARL) * 2 + (H)) * 8192 + chnk + 512], 16, 0, 0); }

#define RDA8(RA, SG) {                                                                \
    ak[0] = *(const short8*)&As[(RA) + 0 * 1024 + (SG)];                              \
    ak[1] = *(const short8*)&As[(RA) + 1 * 1024 + (SG)];                              \
    ak[2] = *(const short8*)&As[(RA) + 2 * 1024 + (SG)];                              \
    ak[3] = *(const short8*)&As[(RA) + 3 * 1024 + (SG)];                              \
    ak[4] = *(const short8*)&As[(RA) + 4 * 1024 + (SG)];                              \
    ak[5] = *(const short8*)&As[(RA) + 5 * 1024 + (SG)];                              \
    ak[6] = *(const short8*)&As[(RA) + 6 * 1024 + (SG)];                              \
    ak[7] = *(const short8*)&As[(RA) + 7 * 1024 + (SG)]; }

#define LDB8(RB) { _Pragma("unroll") for (int n = 0; n < 4; ++n) {                    \
    bfr[n][0] = *(const short8*)&Bs[(RB) + n * 1024 + sg0];                           \
    bfr[n][1] = *(const short8*)&Bs[(RB) + n * 1024 + sg1]; } }

#define MFMA32(KK) { __builtin_amdgcn_s_setprio(1);                                   \
    _Pragma("unroll") for (int mi = 0; mi < 8; ++mi)                                  \
        _Pragma("unroll") for (int n = 0; n < 4; ++n)                                 \
            acc[mi][n] = __builtin_amdgcn_mfma_f32_16x16x32_bf16(                     \
                ak[mi], bfr[n][KK], acc[mi][n], 0, 0, 0);                             \
    __builtin_amdgcn_s_setprio(0); }

#define BAR  __builtin_amdgcn_s_barrier()
#define WLGN(n) { asm volatile("s_waitcnt lgkmcnt(" #n ")" ::: "memory");             \
                  __builtin_amdgcn_sched_barrier(0); }
#define VMC(n)  asm volatile("s_waitcnt vmcnt(" #n ")" ::: "memory")

// One K-tile, 2 barriers, k-step order (SGX,KX) then (SGY,KY).
#define TILE2G(RA, RB, APAR_N, BPAR_T, OFF_A, OFF_B, DO_A, DO_B, LAST, DRAIN0, SGX, KX, SGY, KY) { \
    LDB8(RB);                                                                         \
    RDA8(RA, SGX);                                                                    \
    if (DO_A) { STGA(0, APAR_N, OFF_A); STGA(1, APAR_N, OFF_A); }                     \
    WLGN(8);                                                                          \
    BAR;                                                                              \
    if (DO_B) { STGB(0, BPAR_T, OFF_B); STGB(1, BPAR_T, OFF_B); }                     \
    WLGN(0);                                                                          \
    MFMA32(KX);                                                                       \
    RDA8(RA, SGY);                                                                    \
    WLGN(0);                                                                          \
    MFMA32(KY);                                                                       \
    if (!(LAST)) {                                                                    \
        if (DRAIN0) { VMC(0); } else { VMC(4); }                                      \
        BAR;                                                                          \
    } }

#define KLOOP(SGX, KX, SGY, KY) {                                                     \
    for (int t = 0; t + 3 < NT; t += 2) {                                             \
        const long o1 = ((long)t + 1) << 6;                                           \
        const long o2 = o1 + 64;                                                      \
        const long o3 = o2 + 64;                                                      \
        TILE2G(rA0, rB0, 1, 0, o1, o2, true, true, false, false, SGX, KX, SGY, KY);   \
        TILE2G(rA1, rB1, 0, 1, o2, o3, true, true, false, false, SGX, KX, SGY, KY);   \
    }                                                                                 \
    {                                                                                 \
        const long o1 = ((long)NT - 1) << 6;                                          \
        TILE2G(rA0, rB0, 1, 0, o1, 0, true, false, false, true, SGX, KX, SGY, KY);    \
        TILE2G(rA1, rB1, 0, 1, 0, 0, false, false, true, false, SGX, KX, SGY, KY);    \
    } }

    f32x4 acc[8][4];
#pragma unroll
    for (int m = 0; m < 8; ++m)
#pragma unroll
        for (int n = 0; n < 4; ++n) acc[m][n] = (f32x4){0.f, 0.f, 0.f, 0.f};

    short8 ak[8], bfr[4][2];

    // ---- prologue: B(0),A(0) -> par0; B(1) -> par1; keep B(1) in flight ----
    STGB(0, 0, 0); STGB(1, 0, 0);
    STGA(0, 0, 0); STGA(1, 0, 0);
    STGB(0, 1, 64); STGB(1, 1, 64);
    VMC(4);
    BAR;

    if (gA) { KLOOP(sg0, 0, sg1, 1); }
    else    { KLOOP(sg1, 1, sg0, 0); }

    // ---- epilogue: C/D layout col = lane&15, row = (lane>>4)*4 + reg ----
#pragma unroll
    for (int n = 0; n < 4; ++n) {
        long col = bn + wn * 64 + n * 16 + l15;
        float bv = bias[col];
#pragma unroll
        for (int m = 0; m < 8; ++m) {
            long row = bm + wm * 128 + m * 16 + q4 * 4;
#pragma unroll
            for (int r = 0; r < 4; ++r)
                out[(row + r) * (long)N + col] = acc[m][n][r] + bv;
        }
    }
#undef STGA
#undef STGB
#undef RDA8
#undef LDB8
#undef MFMA32
#undef BAR
#undef WLGN
#undef VMC
#undef TILE2G
#undef KLOOP
}

// ---------------- fallback 128x128 GEMM (handles fused / odd shapes) ----------------

template <bool PRE_A, bool PRE_B>
__global__ __launch_bounds__(256, 2)
void gemm_kernel(const float* __restrict__ x, const int* __restrict__ wq,
                 const float* __restrict__ scales, const float* __restrict__ bias,
                 const short* __restrict__ Xb, const short* __restrict__ Wb,
                 float* __restrict__ out, int M, int N, int K) {
    constexpr int BM = 128, BN = 128, BK = 64;
    __shared__ alignas(16) short As[BM * BK];
    __shared__ alignas(16) short Bs[BN * BK];

    const int nM = M / BM, nN = N / BN;
    int bid = blockIdx.x;
    int pm, pn;
    const int G = 8;
    if ((nN % G) == 0) {
        int per = nM * G;
        int grp = bid / per;
        int in  = bid % per;
        pn = grp * G + (in % G);
        pm = in / G;
    } else {
        pn = bid % nN;
        pm = bid / nN;
    }

    const int tid  = threadIdx.x;
    const int lane = tid & 63;
    const int wv   = tid >> 6;
    const int wm   = (wv >> 1) * 64;
    const int wn   = (wv & 1) * 64;
    const int q    = lane >> 4;
    const int l15  = lane & 15;
    const int sxor = lane & 7;

    const long bm = (long)pm * BM, bn = (long)pn * BN;

    f32x4 acc[4][4];
#pragma unroll
    for (int i = 0; i < 4; ++i)
#pragma unroll
        for (int j = 0; j < 4; ++j) acc[i][j] = (f32x4){0.f, 0.f, 0.f, 0.f};

    const int srow = tid >> 3;
    const int scg  = tid & 7;

    const int sg0   = q ^ sxor;
    const int aOff0 = (wm + l15) * 64 + sg0 * 8;
    const int aOff1 = (wm + l15) * 64 + (sg0 ^ 4) * 8;
    const int bOff0 = (wn + l15) * 64 + sg0 * 8;
    const int bOff1 = (wn + l15) * 64 + (sg0 ^ 4) * 8;

    const int prRow  = lane >> 3;
    const int prGsrc = (lane & 7) ^ (lane >> 3);

    for (int k0 = 0; k0 < K; k0 += BK) {
        if constexpr (PRE_A) {
#pragma unroll
            for (int i = 0; i < 4; ++i) {
                int r = wv * 32 + i * 8 + prRow;
                const short* src = Xb + (bm + r) * (long)K + k0 + prGsrc * 8;
                __builtin_amdgcn_global_load_lds((const AS1 void*)src,
                                                 (AS3 void*)&As[(wv * 32 + i * 8) * 64],
                                                 16, 0, 0);
            }
        } else {
#pragma unroll
            for (int i = 0; i < 4; ++i) {
                int r = i * 32 + srow;
                const float4* p = (const float4*)(x + (bm + r) * (long)K + k0 + scg * 8);
                float4 f0 = p[0], f1 = p[1];
                short8 v;
                v[0] = f2bf(f0.x); v[1] = f2bf(f0.y); v[2] = f2bf(f0.z); v[3] = f2bf(f0.w);
                v[4] = f2bf(f1.x); v[5] = f2bf(f1.y); v[6] = f2bf(f1.z); v[7] = f2bf(f1.w);
                int sg = scg ^ (r & 7);
                *(short8*)&As[r * 64 + sg * 8] = v;
            }
        }
        if constexpr (PRE_B) {
#pragma unroll
            for (int i = 0; i < 4; ++i) {
                int r = wv * 32 + i * 8 + prRow;
                const short* src = Wb + (bn + r) * (long)K + k0 + prGsrc * 8;
                __builtin_amdgcn_global_load_lds((const AS1 void*)src,
                                                 (AS3 void*)&Bs[(wv * 32 + i * 8) * 64],
                                                 16, 0, 0);
            }
        } else {
#pragma unroll
            for (int i = 0; i < 4; ++i) {
                int r = i * 32 + srow;
                const int4* p = (const int4*)(wq + (bn + r) * (long)K + k0 + scg * 8);
                int4 q0 = p[0], q1 = p[1];
                float s = scales[(bn + r) * (long)(K >> 5) + ((k0 + scg * 8) >> 5)];
                short8 v;
                v[0] = f2bf((float)(q0.x - 128) * s);
                v[1] = f2bf((float)(q0.y - 128) * s);
                v[2] = f2bf((float)(q0.z - 128) * s);
                v[3] = f2bf((float)(q0.w - 128) * s);
                v[4] = f2bf((float)(q1.x - 128) * s);
                v[5] = f2bf((float)(q1.y - 128) * s);
                v[6] = f2bf((float)(q1.z - 128) * s);
                v[7] = f2bf((float)(q1.w - 128) * s);
                int sg = scg ^ (r & 7);
                *(short8*)&Bs[r * 64 + sg * 8] = v;
            }
        }
        __syncthreads();

#pragma unroll
        for (int kk = 0; kk < 2; ++kk) {
            short8 a[4], b[4];
            const int aBase = kk ? aOff1 : aOff0;
            const int bBase = kk ? bOff1 : bOff0;
#pragma unroll
            for (int mi = 0; mi < 4; ++mi) a[mi] = *(const short8*)&As[aBase + mi * 16 * 64];
#pragma unroll
            for (int nj = 0; nj < 4; ++nj) b[nj] = *(const short8*)&Bs[bBase + nj * 16 * 64];
#pragma unroll
            for (int mi = 0; mi < 4; ++mi)
#pragma unroll
                for (int nj = 0; nj < 4; ++nj)
                    acc[mi][nj] = __builtin_amdgcn_mfma_f32_16x16x32_bf16(
                        a[mi], b[nj], acc[mi][nj], 0, 0, 0);
        }
        __syncthreads();
    }

#pragma unroll
    for (int nj = 0; nj < 4; ++nj) {
        long col = bn + wn + nj * 16 + l15;
        float bv = bias[col];
#pragma unroll
        for (int mi = 0; mi < 4; ++mi) {
            long row = bm + wm + mi * 16 + q * 4;
#pragma unroll
            for (int r2 = 0; r2 < 4; ++r2)
                out[(row + r2) * (long)N + col] = acc[mi][nj][r2] + bv;
        }
    }
}

// ---------------- launch ----------------

extern "C" void kernel_launch(void* const* d_in, const int* in_sizes, int n_in,
                              void* d_out, int out_size, void* d_ws, size_t ws_size,
                              hipStream_t stream) {
    const float* x      = (const float*)d_in[0];
    const int*   wq     = (const int*)d_in[1];
    const float* scales = (const float*)d_in[2];
    const float* bias   = (const float*)d_in[3];
    float*       out    = (float*)d_out;

    const long N = (long)in_sizes[3];
    const long K = (long)in_sizes[1] / N;
    const long M = (long)in_sizes[0] / K;

    const size_t needW = (size_t)N * K * sizeof(short);
    const size_t needX = (size_t)M * K * sizeof(short);

    short* Wb = (short*)d_ws;
    short* Xb = Wb + (size_t)N * K;

    const bool preB = (d_ws != nullptr) && ws_size >= needW;
    const bool preA = preB && ws_size >= (needW + needX);

    if (preB) {
        long t8 = N * K / 8;
        prepack_w_kernel<<<dim3((unsigned)((t8 + 255) / 256)), dim3(256), 0, stream>>>(
            wq, scales, Wb, t8);
    }
    if (preA) {
        long t8 = M * K / 8;
        prepack_x_kernel<<<dim3((unsigned)((t8 + 255) / 256)), dim3(256), 0, stream>>>(
            x, Xb, t8);
    }

    const long NTl = K / 64;
    const bool big = preA && (M % 256 == 0) && (N % 256 == 0) && (K % 64 == 0) &&
                     (NTl >= 4) && (NTl % 2 == 0);

    if (big) {
        dim3 grid((unsigned)((M / 256) * (N / 256))), block(512);
        gemm256_kernel<<<grid, block, 0, stream>>>(bias, Xb, Wb, out, (int)M, (int)N, (int)K);
    } else {
        dim3 grid((unsigned)((M / 128) * (N / 128))), block(256);
        if (preA)
            gemm_kernel<true, true><<<grid, block, 0, stream>>>(x, wq, scales, bias, Xb, Wb,
                                                                out, (int)M, (int)N, (int)K);
        else if (preB)
            gemm_kernel<false, true><<<grid, block, 0, stream>>>(x, wq, scales, bias, Xb, Wb,
                                                                 out, (int)M, (int)N, (int)K);
        else
            gemm_kernel<false, false><<<grid, block, 0, stream>>>(x, wq, scales, bias, Xb, Wb,
                                                                  out, (int)M, (int)N, (int)K);
    }
}

// Round 14
// 603.119 us; speedup vs baseline: 1.1145x; 1.0123x over previous
//
#include <hip/hip_runtime.h>
#include <hip/hip_bf16.h>

typedef __attribute__((ext_vector_type(8))) short short8;
typedef __attribute__((ext_vector_type(4))) float f32x4;

#define AS1 __attribute__((address_space(1)))
#define AS3 __attribute__((address_space(3)))

static __device__ __forceinline__ short f2bf(float f) {
    __hip_bfloat16 h = __float2bfloat16(f);
    union { __hip_bfloat16 h; short s; } u;
    u.h = h;
    return u.s;
}

// ---------------- prepack kernels ----------------

__global__ __launch_bounds__(256) void prepack_w_kernel(const int* __restrict__ wq,
                                                        const float* __restrict__ scales,
                                                        short* __restrict__ Wb,
                                                        long total8) {
    long i = (long)blockIdx.x * 256 + threadIdx.x;
    if (i >= total8) return;
    const int4* p = (const int4*)wq + i * 2;
    int4 q0 = p[0], q1 = p[1];
    float s = scales[(i * 8) >> 5];
    short8 v;
    v[0] = f2bf((float)(q0.x - 128) * s);
    v[1] = f2bf((float)(q0.y - 128) * s);
    v[2] = f2bf((float)(q0.z - 128) * s);
    v[3] = f2bf((float)(q0.w - 128) * s);
    v[4] = f2bf((float)(q1.x - 128) * s);
    v[5] = f2bf((float)(q1.y - 128) * s);
    v[6] = f2bf((float)(q1.z - 128) * s);
    v[7] = f2bf((float)(q1.w - 128) * s);
    ((short8*)Wb)[i] = v;
}

__global__ __launch_bounds__(256) void prepack_x_kernel(const float* __restrict__ x,
                                                        short* __restrict__ Xb,
                                                        long total8) {
    long i = (long)blockIdx.x * 256 + threadIdx.x;
    if (i >= total8) return;
    const float4* p = (const float4*)x + i * 2;
    float4 f0 = p[0], f1 = p[1];
    short8 v;
    v[0] = f2bf(f0.x); v[1] = f2bf(f0.y); v[2] = f2bf(f0.z); v[3] = f2bf(f0.w);
    v[4] = f2bf(f1.x); v[5] = f2bf(f1.y); v[6] = f2bf(f1.z); v[7] = f2bf(f1.w);
    ((short8*)Xb)[i] = v;
}

// -------- 256x256 GEMM: anti-phase wave groups, 2 barriers / K-tile --------
// 512 thr = 8 waves (2M x 4N), per-wave C = 128x64 (8 m x 4 n frags), BK=64.
// LDS: A/B each [par*2+half][128x64 bf16], granule(16B) XOR swizzle (0-conflict,
// measured R5/R10).
// ANTI-PHASE: waves 0-3 compute k-step s0 then s1; waves 4-7 compute s1 then s0.
// With round-robin wave->SIMD mapping each SIMD holds one wave of each group, so
// one wave's second A-read burst drains under the other's MFMA cluster.
// Tile t (parity p), per wave:
//   LDB8(p) [8]; RDA8(p, s_first) [8]; STGA(t+1 -> p^1) [4];
//   WLGN(8)  -- own B-reads complete
//   BAR #1   -- ALL waves' B(p)-reads complete  => B(t+2)->p overwrite safe
//   STGB(t+2 -> p) [4]
//   WLGN(0); MFMA32(s_first);
//   RDA8(p, s_second); WLGN(0); MFMA32(s_second);
//   VMC(4); BAR #2 (boundary)
// Ledger: entering tile t in-flight = [B(t+1):4]; +A(t+1)+B(t+2) -> 12;
// VMC(4) forces B(t+1)+A(t+1) (needed next tile), keeps B(t+2) in flight.
// A(t+1)->p^1 overwrite guard: tile t-1's reads of p^1 all complete before
// boundary BAR of t-1 (each wave's WLGN(0) precedes it). Removed R10's two
// mid-tile barriers (they guarded nothing; audit above).
__global__ __launch_bounds__(512, 2)
void gemm256_kernel(const float* __restrict__ bias,
                    const short* __restrict__ Xb, const short* __restrict__ Wb,
                    float* __restrict__ out, int M, int N, int K) {
    __shared__ alignas(16) short As[4 * 8192];
    __shared__ alignas(16) short Bs[4 * 8192];

    const int nM = M >> 8, nN = N >> 8;
    int bid = blockIdx.x;
    {
        int nwg = nM * nN;
        if ((nwg & 7) == 0) bid = (bid & 7) * (nwg >> 3) + (bid >> 3);  // XCD swizzle
    }
    int pm, pn;
    {
        const int G = 8;
        if ((nN % G) == 0) {
            int per = nM * G;
            int grp = bid / per, in = bid % per;
            pn = grp * G + (in % G);
            pm = in / G;
        } else { pn = bid % nN; pm = bid / nN; }
    }

    const int tid  = threadIdx.x;
    const int lane = tid & 63;
    const int wid  = tid >> 6;
    const int wm   = wid >> 2;     // 0..1
    const int wn   = wid & 3;      // 0..3
    const int q4   = lane >> 4;
    const int l15  = lane & 15;
    const int lx   = lane & 7;
    const bool gA  = (wid >> 2) == 0;   // wave group: 0-3 s0-first, 4-7 s1-first

    const long bm = (long)pm << 8, bn = (long)pn << 8;
    const long Kl = K;
    const int  NT = K >> 6;

    // per-parity read bases (shorts); R5/R10's conflict-free pattern
    const int rA0 = wm * 8192 + l15 * 64;
    const int rA1 = (2 + wm) * 8192 + l15 * 64;
    const int rB0 = (wn >> 1) * 8192 + ((wn & 1) * 64 + l15) * 64;
    const int rB1 = rB0 + 2 * 8192;
    const int sg0 = (q4 ^ lx) * 8;        // k-step 0 granule (swizzled)
    const int sg1 = ((4 + q4) ^ lx) * 8;  // k-step 1

    // staging geometry (identical to R5/R10)
    const int chnk    = wid * 1024;
    const int srowrel = wid * 16 + (lane >> 3);
    const int scol    = ((lane & 7) ^ (lane >> 3)) * 8;

    const short* aS00 = Xb + (bm + 0   + srowrel + 0) * Kl + scol;
    const short* aS01 = Xb + (bm + 0   + srowrel + 8) * Kl + scol;
    const short* aS10 = Xb + (bm + 128 + srowrel + 0) * Kl + scol;
    const short* aS11 = Xb + (bm + 128 + srowrel + 8) * Kl + scol;
    const short* bS00 = Wb + (bn + 0   + srowrel + 0) * Kl + scol;
    const short* bS01 = Wb + (bn + 0   + srowrel + 8) * Kl + scol;
    const short* bS10 = Wb + (bn + 128 + srowrel + 0) * Kl + scol;
    const short* bS11 = Wb + (bn + 128 + srowrel + 8) * Kl + scol;

#define STGA(H, PARL, OFF) {                                                          \
    __builtin_amdgcn_global_load_lds((const AS1 void*)(aS##H##0 + (OFF)),             \
        (AS3 void*)&As[((PARL) * 2 + (H)) * 8192 + chnk], 16, 0, 0);                  \
    __builtin_amdgcn_global_load_lds((const AS1 void*)(aS##H##1 + (OFF)),             \
        (AS3 void*)&As[((PARL) * 2 + (H)) * 8192 + chnk + 512], 16, 0, 0); }
#define STGB(H, PARL, OFF) {                                                          \
    __builtin_amdgcn_global_load_lds((const AS1 void*)(bS##H##0 + (OFF)),             \
        (AS3 void*)&Bs[((PARL) * 2 + (H)) * 8192 + chnk], 16, 0, 0);                  \
    __builtin_amdgcn_global_load_lds((const AS1 void*)(bS##H##1 + (OFF)),             \
        (AS3 void*)&Bs[((PARL) * 2 + (H)) * 8192 + chnk + 512], 16, 0, 0); }

#define RDA8(RA, SG) {                                                                \
    ak[0] = *(const short8*)&As[(RA) + 0 * 1024 + (SG)];                              \
    ak[1] = *(const short8*)&As[(RA) + 1 * 1024 + (SG)];                              \
    ak[2] = *(const short8*)&As[(RA) + 2 * 1024 + (SG)];                              \
    ak[3] = *(const short8*)&As[(RA) + 3 * 1024 + (SG)];                              \
    ak[4] = *(const short8*)&As[(RA) + 4 * 1024 + (SG)];                              \
    ak[5] = *(const short8*)&As[(RA) + 5 * 1024 + (SG)];                              \
    ak[6] = *(const short8*)&As[(RA) + 6 * 1024 + (SG)];                              \
    ak[7] = *(const short8*)&As[(RA) + 7 * 1024 + (SG)]; }

#define LDB8(RB) { _Pragma("unroll") for (int n = 0; n < 4; ++n) {                    \
    bfr[n][0] = *(const short8*)&Bs[(RB) + n * 1024 + sg0];                           \
    bfr[n][1] = *(const short8*)&Bs[(RB) + n * 1024 + sg1]; } }

#define MFMA32(KK) { __builtin_amdgcn_s_setprio(1);                                   \
    _Pragma("unroll") for (int mi = 0; mi < 8; ++mi)                                  \
        _Pragma("unroll") for (int n = 0; n < 4; ++n)                                 \
            acc[mi][n] = __builtin_amdgcn_mfma_f32_16x16x32_bf16(                     \
                ak[mi], bfr[n][KK], acc[mi][n], 0, 0, 0);                             \
    __builtin_amdgcn_s_setprio(0); }

#define BAR  __builtin_amdgcn_s_barrier()
#define WLGN(n) { asm volatile("s_waitcnt lgkmcnt(" #n ")" ::: "memory");             \
                  __builtin_amdgcn_sched_barrier(0); }
#define VMC(n)  asm volatile("s_waitcnt vmcnt(" #n ")" ::: "memory")

// One K-tile, 2 barriers, k-step order (SGX,KX) then (SGY,KY).
#define TILE2G(RA, RB, APAR_N, BPAR_T, OFF_A, OFF_B, DO_A, DO_B, LAST, DRAIN0, SGX, KX, SGY, KY) { \
    LDB8(RB);                                                                         \
    RDA8(RA, SGX);                                                                    \
    if (DO_A) { STGA(0, APAR_N, OFF_A); STGA(1, APAR_N, OFF_A); }                     \
    WLGN(8);                                                                          \
    BAR;                                                                              \
    if (DO_B) { STGB(0, BPAR_T, OFF_B); STGB(1, BPAR_T, OFF_B); }                     \
    WLGN(0);                                                                          \
    MFMA32(KX);                                                                       \
    RDA8(RA, SGY);                                                                    \
    WLGN(0);                                                                          \
    MFMA32(KY);                                                                       \
    if (!(LAST)) {                                                                    \
        if (DRAIN0) { VMC(0); } else { VMC(4); }                                      \
        BAR;                                                                          \
    } }

#define KLOOP(SGX, KX, SGY, KY) {                                                     \
    for (int t = 0; t + 3 < NT; t += 2) {                                             \
        const long o1 = ((long)t + 1) << 6;                                           \
        const long o2 = o1 + 64;                                                      \
        const long o3 = o2 + 64;                                                      \
        TILE2G(rA0, rB0, 1, 0, o1, o2, true, true, false, false, SGX, KX, SGY, KY);   \
        TILE2G(rA1, rB1, 0, 1, o2, o3, true, true, false, false, SGX, KX, SGY, KY);   \
    }                                                                                 \
    {                                                                                 \
        const long o1 = ((long)NT - 1) << 6;                                          \
        TILE2G(rA0, rB0, 1, 0, o1, 0, true, false, false, true, SGX, KX, SGY, KY);    \
        TILE2G(rA1, rB1, 0, 1, 0, 0, false, false, true, false, SGX, KX, SGY, KY);    \
    } }

    f32x4 acc[8][4];
#pragma unroll
    for (int m = 0; m < 8; ++m)
#pragma unroll
        for (int n = 0; n < 4; ++n) acc[m][n] = (f32x4){0.f, 0.f, 0.f, 0.f};

    short8 ak[8], bfr[4][2];

    // ---- prologue: B(0),A(0) -> par0; B(1) -> par1; keep B(1) in flight ----
    STGB(0, 0, 0); STGB(1, 0, 0);
    STGA(0, 0, 0); STGA(1, 0, 0);
    STGB(0, 1, 64); STGB(1, 1, 64);
    VMC(4);
    BAR;

    if (gA) { KLOOP(sg0, 0, sg1, 1); }
    else    { KLOOP(sg1, 1, sg0, 0); }

    // ---- epilogue: C/D layout col = lane&15, row = (lane>>4)*4 + reg ----
#pragma unroll
    for (int n = 0; n < 4; ++n) {
        long col = bn + wn * 64 + n * 16 + l15;
        float bv = bias[col];
#pragma unroll
        for (int m = 0; m < 8; ++m) {
            long row = bm + wm * 128 + m * 16 + q4 * 4;
#pragma unroll
            for (int r = 0; r < 4; ++r)
                out[(row + r) * (long)N + col] = acc[m][n][r] + bv;
        }
    }
#undef STGA
#undef STGB
#undef RDA8
#undef LDB8
#undef MFMA32
#undef BAR
#undef WLGN
#undef VMC
#undef TILE2G
#undef KLOOP
}

// ---------------- fallback 128x128 GEMM (handles fused / odd shapes) ----------------

template <bool PRE_A, bool PRE_B>
__global__ __launch_bounds__(256, 2)
void gemm_kernel(const float* __restrict__ x, const int* __restrict__ wq,
                 const float* __restrict__ scales, const float* __restrict__ bias,
                 const short* __restrict__ Xb, const short* __restrict__ Wb,
                 float* __restrict__ out, int M, int N, int K) {
    constexpr int BM = 128, BN = 128, BK = 64;
    __shared__ alignas(16) short As[BM * BK];
    __shared__ alignas(16) short Bs[BN * BK];

    const int nM = M / BM, nN = N / BN;
    int bid = blockIdx.x;
    int pm, pn;
    const int G = 8;
    if ((nN % G) == 0) {
        int per = nM * G;
        int grp = bid / per;
        int in  = bid % per;
        pn = grp * G + (in % G);
        pm = in / G;
    } else {
        pn = bid % nN;
        pm = bid / nN;
    }

    const int tid  = threadIdx.x;
    const int lane = tid & 63;
    const int wv   = tid >> 6;
    const int wm   = (wv >> 1) * 64;
    const int wn   = (wv & 1) * 64;
    const int q    = lane >> 4;
    const int l15  = lane & 15;
    const int sxor = lane & 7;

    const long bm = (long)pm * BM, bn = (long)pn * BN;

    f32x4 acc[4][4];
#pragma unroll
    for (int i = 0; i < 4; ++i)
#pragma unroll
        for (int j = 0; j < 4; ++j) acc[i][j] = (f32x4){0.f, 0.f, 0.f, 0.f};

    const int srow = tid >> 3;
    const int scg  = tid & 7;

    const int sg0   = q ^ sxor;
    const int aOff0 = (wm + l15) * 64 + sg0 * 8;
    const int aOff1 = (wm + l15) * 64 + (sg0 ^ 4) * 8;
    const int bOff0 = (wn + l15) * 64 + sg0 * 8;
    const int bOff1 = (wn + l15) * 64 + (sg0 ^ 4) * 8;

    const int prRow  = lane >> 3;
    const int prGsrc = (lane & 7) ^ (lane >> 3);

    for (int k0 = 0; k0 < K; k0 += BK) {
        if constexpr (PRE_A) {
#pragma unroll
            for (int i = 0; i < 4; ++i) {
                int r = wv * 32 + i * 8 + prRow;
                const short* src = Xb + (bm + r) * (long)K + k0 + prGsrc * 8;
                __builtin_amdgcn_global_load_lds((const AS1 void*)src,
                                                 (AS3 void*)&As[(wv * 32 + i * 8) * 64],
                                                 16, 0, 0);
            }
        } else {
#pragma unroll
            for (int i = 0; i < 4; ++i) {
                int r = i * 32 + srow;
                const float4* p = (const float4*)(x + (bm + r) * (long)K + k0 + scg * 8);
                float4 f0 = p[0], f1 = p[1];
                short8 v;
                v[0] = f2bf(f0.x); v[1] = f2bf(f0.y); v[2] = f2bf(f0.z); v[3] = f2bf(f0.w);
                v[4] = f2bf(f1.x); v[5] = f2bf(f1.y); v[6] = f2bf(f1.z); v[7] = f2bf(f1.w);
                int sg = scg ^ (r & 7);
                *(short8*)&As[r * 64 + sg * 8] = v;
            }
        }
        if constexpr (PRE_B) {
#pragma unroll
            for (int i = 0; i < 4; ++i) {
                int r = wv * 32 + i * 8 + prRow;
                const short* src = Wb + (bn + r) * (long)K + k0 + prGsrc * 8;
                __builtin_amdgcn_global_load_lds((const AS1 void*)src,
                                                 (AS3 void*)&Bs[(wv * 32 + i * 8) * 64],
                                                 16, 0, 0);
            }
        } else {
#pragma unroll
            for (int i = 0; i < 4; ++i) {
                int r = i * 32 + srow;
                const int4* p = (const int4*)(wq + (bn + r) * (long)K + k0 + scg * 8);
                int4 q0 = p[0], q1 = p[1];
                float s = scales[(bn + r) * (long)(K >> 5) + ((k0 + scg * 8) >> 5)];
                short8 v;
                v[0] = f2bf((float)(q0.x - 128) * s);
                v[1] = f2bf((float)(q0.y - 128) * s);
                v[2] = f2bf((float)(q0.z - 128) * s);
                v[3] = f2bf((float)(q0.w - 128) * s);
                v[4] = f2bf((float)(q1.x - 128) * s);
                v[5] = f2bf((float)(q1.y - 128) * s);
                v[6] = f2bf((float)(q1.z - 128) * s);
                v[7] = f2bf((float)(q1.w - 128) * s);
                int sg = scg ^ (r & 7);
                *(short8*)&Bs[r * 64 + sg * 8] = v;
            }
        }
        __syncthreads();

#pragma unroll
        for (int kk = 0; kk < 2; ++kk) {
            short8 a[4], b[4];
            const int aBase = kk ? aOff1 : aOff0;
            const int bBase = kk ? bOff1 : bOff0;
#pragma unroll
            for (int mi = 0; mi < 4; ++mi) a[mi] = *(const short8*)&As[aBase + mi * 16 * 64];
#pragma unroll
            for (int nj = 0; nj < 4; ++nj) b[nj] = *(const short8*)&Bs[bBase + nj * 16 * 64];
#pragma unroll
            for (int mi = 0; mi < 4; ++mi)
#pragma unroll
                for (int nj = 0; nj < 4; ++nj)
                    acc[mi][nj] = __builtin_amdgcn_mfma_f32_16x16x32_bf16(
                        a[mi], b[nj], acc[mi][nj], 0, 0, 0);
        }
        __syncthreads();
    }

#pragma unroll
    for (int nj = 0; nj < 4; ++nj) {
        long col = bn + wn + nj * 16 + l15;
        float bv = bias[col];
#pragma unroll
        for (int mi = 0; mi < 4; ++mi) {
            long row = bm + wm + mi * 16 + q * 4;
#pragma unroll
            for (int r2 = 0; r2 < 4; ++r2)
                out[(row + r2) * (long)N + col] = acc[mi][nj][r2] + bv;
        }
    }
}

// ---------------- launch ----------------

extern "C" void kernel_launch(void* const* d_in, const int* in_sizes, int n_in,
                              void* d_out, int out_size, void* d_ws, size_t ws_size,
                              hipStream_t stream) {
    const float* x      = (const float*)d_in[0];
    const int*   wq     = (const int*)d_in[1];
    const float* scales = (const float*)d_in[2];
    const float* bias   = (const float*)d_in[3];
    float*       out    = (float*)d_out;

    const long N = (long)in_sizes[3];
    const long K = (long)in_sizes[1] / N;
    const long M = (long)in_sizes[0] / K;

    const size_t needW = (size_t)N * K * sizeof(short);
    const size_t needX = (size_t)M * K * sizeof(short);

    short* Wb = (short*)d_ws;
    short* Xb = Wb + (size_t)N * K;

    const bool preB = (d_ws != nullptr) && ws_size >= needW;
    const bool preA = preB && ws_size >= (needW + needX);

    if (preB) {
        long t8 = N * K / 8;
        prepack_w_kernel<<<dim3((unsigned)((t8 + 255) / 256)), dim3(256), 0, stream>>>(
            wq, scales, Wb, t8);
    }
    if (preA) {
        long t8 = M * K / 8;
        prepack_x_kernel<<<dim3((unsigned)((t8 + 255) / 256)), dim3(256), 0, stream>>>(
            x, Xb, t8);
    }

    const long NTl = K / 64;
    const bool big = preA && (M % 256 == 0) && (N % 256 == 0) && (K % 64 == 0) &&
                     (NTl >= 4) && (NTl % 2 == 0);

    if (big) {
        dim3 grid((unsigned)((M / 256) * (N / 256))), block(512);
        gemm256_kernel<<<grid, block, 0, stream>>>(bias, Xb, Wb, out, (int)M, (int)N, (int)K);
    } else {
        dim3 grid((unsigned)((M / 128) * (N / 128))), block(256);
        if (preA)
            gemm_kernel<true, true><<<grid, block, 0, stream>>>(x, wq, scales, bias, Xb, Wb,
                                                                out, (int)M, (int)N, (int)K);
        else if (preB)
            gemm_kernel<false, true><<<grid, block, 0, stream>>>(x, wq, scales, bias, Xb, Wb,
                                                                 out, (int)M, (int)N, (int)K);
        else
            gemm_kernel<false, false><<<grid, block, 0, stream>>>(x, wq, scales, bias, Xb, Wb,
                                                                  out, (int)M, (int)N, (int)K);
    }
}